// Round 6
// baseline (32.019 us; speedup 1.0000x reference)
//
#include <hip/hip_runtime.h>

// Basket embedding mean-pool.
// item_ids: [B, L, M] int32; basket_lens: [B, L] int32; emb: [VOCAB, H] f32
// out: [B, L, H] f32 ; out[b,l,:] = sum_{m<len} emb[ids[b,l,m]] / max(len,1)
//
// R6: R5 + non-temporal gathers/stores. R2-R5 plateau at ~25 us regardless
// of traffic (R4 halved it: null) or per-wave depth (ring-8 vs burst-20:
// null) -> serialized per-CU cost scales with gather INSTRUCTIONS, pointing
// at L1 return+fill processing (~59 cy/instr). Random gather has ~0% L1
// reuse, so nt loads (no L1 allocate) skip the useless fill; nt store stops
// the 13 MB output from evicting table lines in L2/LLC.

constexpr int Bn = 1024, Ln = 50, Mn = 20, Hn = 64;
constexpr int NB = Bn * Ln;                 // 51200 baskets

typedef float f32x4 __attribute__((ext_vector_type(4)));

__global__ void basket_pool_kernel(
    const int* __restrict__ item_ids,       // [NB, M]
    const int* __restrict__ basket_lens,    // [NB]
    const float* __restrict__ emb,          // [VOCAB, H]
    float* __restrict__ out)                // [NB, H]
{
    const int tid    = blockIdx.x * blockDim.x + threadIdx.x;
    const int basket = tid >> 4;            // 16 lanes per basket
    const int lane4  = (tid & 15) << 2;     // h offset: lane*4
    if (basket >= NB) return;

    const int len = basket_lens[basket];
    const int* __restrict__ ids = item_ids + basket * Mn;

    // preload all 20 ids (5x int4, coalesced within each 16-lane group)
    int idb[Mn];
#pragma unroll
    for (int c = 0; c < Mn / 4; ++c) {
        const int4 t = reinterpret_cast<const int4*>(ids)[c];
        idb[c * 4 + 0] = t.x;
        idb[c * 4 + 1] = t.y;
        idb[c * 4 + 2] = t.z;
        idb[c * 4 + 3] = t.w;
    }
    const int id0 = idb[0];

    // all 20 element-offsets up front (32-bit)
    int off[Mn];
#pragma unroll
    for (int m = 0; m < Mn; ++m) {
        const int e = (m < len) ? idb[m] : id0;   // dup slot (masked later)
        off[m] = e * Hn + lane4;
    }

    // 20 non-temporal gathers back-to-back (no L1 allocate)
    f32x4 v[Mn];
#pragma unroll
    for (int m = 0; m < Mn; ++m)
        v[m] = __builtin_nontemporal_load(
                   reinterpret_cast<const f32x4*>(emb + off[m]));

    // 4 independent accumulate chains, masked weights
    f32x4 a0 = {0.f, 0.f, 0.f, 0.f};
    f32x4 a1 = {0.f, 0.f, 0.f, 0.f};
    f32x4 a2 = {0.f, 0.f, 0.f, 0.f};
    f32x4 a3 = {0.f, 0.f, 0.f, 0.f};
#pragma unroll
    for (int m = 0; m < Mn; m += 4) {
        const float w0 = (m + 0 < len) ? 1.f : 0.f;
        const float w1 = (m + 1 < len) ? 1.f : 0.f;
        const float w2 = (m + 2 < len) ? 1.f : 0.f;
        const float w3 = (m + 3 < len) ? 1.f : 0.f;
        a0 += v[m + 0] * w0;
        a1 += v[m + 1] * w1;
        a2 += v[m + 2] * w2;
        a3 += v[m + 3] * w3;
    }

    const float inv = 1.0f / (float)(len > 0 ? len : 1);
    const f32x4 r = (a0 + a1 + a2 + a3) * inv;

    __builtin_nontemporal_store(
        r, reinterpret_cast<f32x4*>(out + (basket * Hn + lane4)));
}

extern "C" void kernel_launch(void* const* d_in, const int* in_sizes, int n_in,
                              void* d_out, int out_size, void* d_ws, size_t ws_size,
                              hipStream_t stream) {
    const int*   item_ids    = (const int*)d_in[0];    // B*L*M
    const int*   basket_lens = (const int*)d_in[1];    // B*L
    const float* emb         = (const float*)d_in[2];  // VOCAB*H
    float*       out         = (float*)d_out;          // B*L*H

    const int total_threads = NB * 16;                 // 819200
    const int block = 256;
    const int grid  = (total_threads + block - 1) / block;  // 3200
    basket_pool_kernel<<<grid, block, 0, stream>>>(item_ids, basket_lens, emb, out);
}